// Round 1
// baseline (555.178 us; speedup 1.0000x reference)
//
#include <hip/hip_runtime.h>

#define SDIM 4096
#define ALPHA 0.01f
#define WS_ARR 32  // float offset where gathered column arrays start in d_ws

// ws layout (floats):
//   [0] = sum_sq accumulator   (atomicAdd target)
//   [2] = sum3 accumulator     (atomicAdd target)
//   [8..24) = 16 per-block log partials
//   [32 .. 32+5*4096) = c0 | c1 | c3 | t0 | t1  (gathered columns)

// ---------------------------------------------------------------------------
// Kernel 1: gather columns, compute log partials, zero accumulators.
// grid = 16 blocks x 256 threads = 4096 threads (one per row)
// ---------------------------------------------------------------------------
__global__ void k_gather(const float* __restrict__ inp, const float* __restrict__ tgt,
                         float* __restrict__ ws) {
    __shared__ float sbuf[4];
    int n = blockIdx.x * blockDim.x + threadIdx.x;  // 0..4095
    const float* row = inp + (size_t)n * SDIM;
    const float* trow = tgt + (size_t)n * SDIM;
    float* arr = ws + WS_ARR;

    float v0 = row[0], v1 = row[1], v3 = row[3], v4 = row[4];
    arr[n]            = v0;            // c0
    arr[SDIM + n]     = v1;            // c1
    arr[2 * SDIM + n] = v3;            // c3
    arr[3 * SDIM + n] = trow[0];       // t0
    arr[4 * SDIM + n] = trow[1];       // t1

    float lg = logf(v4);
    #pragma unroll
    for (int off = 32; off > 0; off >>= 1) lg += __shfl_down(lg, off);
    if ((threadIdx.x & 63) == 0) sbuf[threadIdx.x >> 6] = lg;
    __syncthreads();
    if (threadIdx.x == 0)
        ws[8 + blockIdx.x] = sbuf[0] + sbuf[1] + sbuf[2] + sbuf[3];
    // zero the atomic accumulators for this call (ws is poisoned each launch)
    if (blockIdx.x == 0 && threadIdx.x < 8) ws[threadIdx.x] = 0.0f;
}

// ---------------------------------------------------------------------------
// Kernel 2: cost matrix. grid = (4, 4096), block = 256.
// blockIdx.y = n (row); each block covers 1024 columns via 4 coalesced
// dword stores per thread (d_out+1 base breaks 16B alignment, so we use
// strided coalesced scalar stores instead of float4).
// ---------------------------------------------------------------------------
__global__ void k_cost(const float* __restrict__ ws, float* __restrict__ out) {
    const float* c0 = ws + WS_ARR;
    const float* c1 = c0 + SDIM;
    const float* t0 = c0 + 3 * SDIM;
    const float* t1 = c0 + 4 * SDIM;

    int n = blockIdx.y;
    float a0 = c0[n];  // wave-uniform -> scalar load
    float a1 = c1[n];
    int base = blockIdx.x * 1024;
    float* orow = out + 1 + (size_t)n * SDIM + base;
    int t = threadIdx.x;
    #pragma unroll
    for (int k = 0; k < 4; ++k) {
        int m = base + k * 256 + t;
        float d0 = a0 - t0[m];
        float d1 = a1 - t1[m];
        orow[k * 256 + t] = 0.5f * (d0 * d0 + d1 * d1);
    }
}

// ---------------------------------------------------------------------------
// Kernel 3: fused reduction over both matrices.
//   sum_sq += (input - target)^2        (all S*S elements)
//   sum3   += (c3[j] - target[i,j])^2   (col-3 broadcast along rows)
// grid = 16384 blocks x 256 threads, one float4 per thread.
// ---------------------------------------------------------------------------
__global__ void k_reduce(const float* __restrict__ inp, const float* __restrict__ tgt,
                         float* __restrict__ ws) {
    __shared__ float s1[4], s2[4];
    const float* c3 = ws + WS_ARR + 2 * SDIM;

    size_t gid = (size_t)blockIdx.x * blockDim.x + threadIdx.x;
    size_t f = gid * 4;                    // flat float index, 16B aligned
    float4 vi = *(const float4*)(inp + f);
    float4 vt = *(const float4*)(tgt + f);
    int j = (int)(f & (SDIM - 1));         // column index of first lane elem
    float4 vc = *(const float4*)(c3 + j);  // L2-hot, aligned

    float a1 = 0.0f, a2 = 0.0f, d;
    d = vi.x - vt.x; a1 += d * d;
    d = vi.y - vt.y; a1 += d * d;
    d = vi.z - vt.z; a1 += d * d;
    d = vi.w - vt.w; a1 += d * d;
    d = vc.x - vt.x; a2 += d * d;
    d = vc.y - vt.y; a2 += d * d;
    d = vc.z - vt.z; a2 += d * d;
    d = vc.w - vt.w; a2 += d * d;

    #pragma unroll
    for (int off = 32; off > 0; off >>= 1) {
        a1 += __shfl_down(a1, off);
        a2 += __shfl_down(a2, off);
    }
    int wave = threadIdx.x >> 6;
    if ((threadIdx.x & 63) == 0) { s1[wave] = a1; s2[wave] = a2; }
    __syncthreads();
    if (threadIdx.x == 0) {
        float t1v = s1[0] + s1[1] + s1[2] + s1[3];
        float t2v = s2[0] + s2[1] + s2[2] + s2[3];
        atomicAdd(&ws[0], t1v);
        atomicAdd(&ws[2], t2v);
    }
}

// ---------------------------------------------------------------------------
// Kernel 4: combine partials into the scalar loss.
//   loss = ALPHA * sum_sq - S * sum_log + sum3 / (S*S)
// ---------------------------------------------------------------------------
__global__ void k_final(const float* __restrict__ ws, float* __restrict__ out) {
    if (threadIdx.x == 0) {
        float slog = 0.0f;
        #pragma unroll
        for (int i = 0; i < 16; ++i) slog += ws[8 + i];
        float loss = ALPHA * ws[0] - (float)SDIM * slog
                   + ws[2] * (1.0f / ((float)SDIM * (float)SDIM));
        out[0] = loss;
    }
}

extern "C" void kernel_launch(void* const* d_in, const int* in_sizes, int n_in,
                              void* d_out, int out_size, void* d_ws, size_t ws_size,
                              hipStream_t stream) {
    const float* inp = (const float*)d_in[0];
    const float* tgt = (const float*)d_in[1];
    float* out = (float*)d_out;
    float* ws  = (float*)d_ws;

    k_gather<<<16, 256, 0, stream>>>(inp, tgt, ws);
    k_cost<<<dim3(4, 4096), 256, 0, stream>>>(ws, out);
    k_reduce<<<16384, 256, 0, stream>>>(inp, tgt, ws);
    k_final<<<1, 64, 0, stream>>>(ws, out);
}

// Round 2
// 180.765 us; speedup vs baseline: 3.0713x; 3.0713x over previous
//
#include <hip/hip_runtime.h>

#define SDIM 4096
#define ALPHA 0.01f
#define WS_ARR 32            // float offset where gathered column arrays start
#define RBLOCKS 2048         // k_reduce grid size
#define WS_PART (WS_ARR + 5 * SDIM)  // per-block partials: [WS_PART, WS_PART+2*RBLOCKS)

// ws layout (floats):
//   [8..24)                      16 per-block log partials (k_gather)
//   [32 .. 32+5*4096)            c0 | c1 | c3 | t0 | t1  (gathered columns)
//   [WS_PART .. WS_PART+2048)    per-block sum_sq partials (k_reduce)
//   [.. +2048)                   per-block sum3 partials   (k_reduce)

// ---------------------------------------------------------------------------
// Kernel 1: gather columns, compute log partials.
// grid = 16 blocks x 256 threads = 4096 threads (one per row)
// ---------------------------------------------------------------------------
__global__ void k_gather(const float* __restrict__ inp, const float* __restrict__ tgt,
                         float* __restrict__ ws) {
    __shared__ float sbuf[4];
    int n = blockIdx.x * blockDim.x + threadIdx.x;  // 0..4095
    const float* row = inp + (size_t)n * SDIM;
    const float* trow = tgt + (size_t)n * SDIM;
    float* arr = ws + WS_ARR;

    float v0 = row[0], v1 = row[1], v3 = row[3], v4 = row[4];
    arr[n]            = v0;            // c0
    arr[SDIM + n]     = v1;            // c1
    arr[2 * SDIM + n] = v3;            // c3
    arr[3 * SDIM + n] = trow[0];       // t0
    arr[4 * SDIM + n] = trow[1];       // t1

    float lg = logf(v4);
    #pragma unroll
    for (int off = 32; off > 0; off >>= 1) lg += __shfl_down(lg, off);
    if ((threadIdx.x & 63) == 0) sbuf[threadIdx.x >> 6] = lg;
    __syncthreads();
    if (threadIdx.x == 0)
        ws[8 + blockIdx.x] = sbuf[0] + sbuf[1] + sbuf[2] + sbuf[3];
}

// ---------------------------------------------------------------------------
// Kernel 2: cost matrix. grid = (4, 4096), block = 256.
// blockIdx.y = n (row); strided coalesced dword stores (out+1 base is
// 4B-aligned only).
// ---------------------------------------------------------------------------
__global__ void k_cost(const float* __restrict__ ws, float* __restrict__ out) {
    const float* c0 = ws + WS_ARR;
    const float* c1 = c0 + SDIM;
    const float* t0 = c0 + 3 * SDIM;
    const float* t1 = c0 + 4 * SDIM;

    int n = blockIdx.y;
    float a0 = c0[n];  // wave-uniform -> scalar load
    float a1 = c1[n];
    int base = blockIdx.x * 1024;
    float* orow = out + 1 + (size_t)n * SDIM + base;
    int t = threadIdx.x;
    #pragma unroll
    for (int k = 0; k < 4; ++k) {
        int m = base + k * 256 + t;
        float d0 = a0 - t0[m];
        float d1 = a1 - t1[m];
        orow[k * 256 + t] = 0.5f * (d0 * d0 + d1 * d1);
    }
}

// ---------------------------------------------------------------------------
// Kernel 3: fused reduction over both matrices (atomic-free).
//   sum_sq partial: (input - target)^2     over all S*S elements
//   sum3 partial:   (c3[j] - target[i,j])^2
// grid = RBLOCKS x 256; grid-stride loop, one float4 per iteration (8 iters).
// Per-block partials written to distinct ws slots — no contended atomics.
// ---------------------------------------------------------------------------
__global__ void k_reduce(const float* __restrict__ inp, const float* __restrict__ tgt,
                         float* __restrict__ ws) {
    __shared__ float s1[4], s2[4];
    const float* c3 = ws + WS_ARR + 2 * SDIM;

    const size_t nvec = (size_t)SDIM * SDIM / 4;  // float4 count
    float a1 = 0.0f, a2 = 0.0f;
    for (size_t v = (size_t)blockIdx.x * blockDim.x + threadIdx.x; v < nvec;
         v += (size_t)gridDim.x * blockDim.x) {
        size_t f = v * 4;
        float4 vi = *(const float4*)(inp + f);
        float4 vt = *(const float4*)(tgt + f);
        float4 vc = *(const float4*)(c3 + (int)(f & (SDIM - 1)));  // L2-hot
        float d;
        d = vi.x - vt.x; a1 += d * d;
        d = vi.y - vt.y; a1 += d * d;
        d = vi.z - vt.z; a1 += d * d;
        d = vi.w - vt.w; a1 += d * d;
        d = vc.x - vt.x; a2 += d * d;
        d = vc.y - vt.y; a2 += d * d;
        d = vc.z - vt.z; a2 += d * d;
        d = vc.w - vt.w; a2 += d * d;
    }

    #pragma unroll
    for (int off = 32; off > 0; off >>= 1) {
        a1 += __shfl_down(a1, off);
        a2 += __shfl_down(a2, off);
    }
    int wave = threadIdx.x >> 6;
    if ((threadIdx.x & 63) == 0) { s1[wave] = a1; s2[wave] = a2; }
    __syncthreads();
    if (threadIdx.x == 0) {
        ws[WS_PART + blockIdx.x]           = s1[0] + s1[1] + s1[2] + s1[3];
        ws[WS_PART + RBLOCKS + blockIdx.x] = s2[0] + s2[1] + s2[2] + s2[3];
    }
}

// ---------------------------------------------------------------------------
// Kernel 4: reduce the 2*RBLOCKS partials + 16 log partials, emit loss.
// One block of 256 threads.
//   loss = ALPHA * sum_sq - S * sum_log + sum3 / (S*S)
// ---------------------------------------------------------------------------
__global__ void k_final(const float* __restrict__ ws, float* __restrict__ out) {
    __shared__ float s1[4], s2[4];
    float a1 = 0.0f, a2 = 0.0f;
    for (int i = threadIdx.x; i < RBLOCKS; i += 256) {
        a1 += ws[WS_PART + i];
        a2 += ws[WS_PART + RBLOCKS + i];
    }
    #pragma unroll
    for (int off = 32; off > 0; off >>= 1) {
        a1 += __shfl_down(a1, off);
        a2 += __shfl_down(a2, off);
    }
    int wave = threadIdx.x >> 6;
    if ((threadIdx.x & 63) == 0) { s1[wave] = a1; s2[wave] = a2; }
    __syncthreads();
    if (threadIdx.x == 0) {
        float sum_sq = s1[0] + s1[1] + s1[2] + s1[3];
        float sum3   = s2[0] + s2[1] + s2[2] + s2[3];
        float slog = 0.0f;
        #pragma unroll
        for (int i = 0; i < 16; ++i) slog += ws[8 + i];
        out[0] = ALPHA * sum_sq - (float)SDIM * slog
               + sum3 * (1.0f / ((float)SDIM * (float)SDIM));
    }
}

extern "C" void kernel_launch(void* const* d_in, const int* in_sizes, int n_in,
                              void* d_out, int out_size, void* d_ws, size_t ws_size,
                              hipStream_t stream) {
    const float* inp = (const float*)d_in[0];
    const float* tgt = (const float*)d_in[1];
    float* out = (float*)d_out;
    float* ws  = (float*)d_ws;

    k_gather<<<16, 256, 0, stream>>>(inp, tgt, ws);
    k_cost<<<dim3(4, 4096), 256, 0, stream>>>(ws, out);
    k_reduce<<<RBLOCKS, 256, 0, stream>>>(inp, tgt, ws);
    k_final<<<1, 256, 0, stream>>>(ws, out);
}